// Round 1
// baseline (1067.237 us; speedup 1.0000x reference)
//
#include <hip/hip_runtime.h>
#include <cstdint>
#include <cstddef>

#define B 32
#define H 12
#define L 512
#define D 768
#define KSEL 255

// workspace byte offsets
#define OFF_IMP   0          // double[B*L]    131072
#define OFF_ATT   131072     // float[B*L]      65536
#define OFF_SENT  196608     // float[B*D]      98304
#define OFF_Q     294912     // float[B*D]      98304
#define OFF_A     393216     // float[B*H*D]  1179648
#define OFF_CB    1572864    // float[B*H]       1536
#define OFF_LG    1574400    // float[B*H*L]   786432
#define OFF_Y     2360832    // float[B*H*D]  1179648
#define OFF_SEL   3540480    // int[B*KSEL]     32640
#define OFF_CTX   3573120    // float[B*D]      98304
#define WS_NEED   3671424

// ---- 1. imp[b,j] = sum_{h,l} amf[l]*sas[b,h,l,j]  (double accumulation) ----
__global__ __launch_bounds__(128) void k_imp(const float* __restrict__ sas,
                                             const float* __restrict__ am,
                                             double* __restrict__ imp) {
  const int b = blockIdx.x, h = blockIdx.y, ch = blockIdx.z;  // ch: 4 chunks of 128 rows
  const int t = threadIdx.x;                                  // 128 threads, float4 each
  const float* base = sas + (((size_t)(b * H + h)) * L + (size_t)ch * 128) * L;
  const float* amb = am + b * L + ch * 128;
  double a0 = 0, a1 = 0, a2 = 0, a3 = 0;
#pragma unroll 4
  for (int l = 0; l < 128; ++l) {
    const float m = (amb[l] > -10.0f) ? 1.0f : 0.0f;
    const float4 v = reinterpret_cast<const float4*>(base + (size_t)l * L)[t];
    a0 += (double)(m * v.x);
    a1 += (double)(m * v.y);
    a2 += (double)(m * v.z);
    a3 += (double)(m * v.w);
  }
  double* ip = imp + b * L + t * 4;
  atomicAdd(ip + 0, a0);
  atomicAdd(ip + 1, a1);
  atomicAdd(ip + 2, a2);
  atomicAdd(ip + 3, a3);
}

// ---- 2. att[b,l] = softmax(am[b,:]) ----
__global__ __launch_bounds__(512) void k_att(const float* __restrict__ am,
                                             float* __restrict__ att) {
  const int b = blockIdx.x, l = threadIdx.x;
  __shared__ float r1[8], r2[8];
  float x = am[b * L + l];
  float m = x;
#pragma unroll
  for (int o = 32; o; o >>= 1) m = fmaxf(m, __shfl_down(m, o));
  if ((l & 63) == 0) r1[l >> 6] = m;
  __syncthreads();
  if (l == 0) {
    float mm = r1[0];
    for (int i = 1; i < 8; ++i) mm = fmaxf(mm, r1[i]);
    r1[0] = mm;
  }
  __syncthreads();
  const float M = r1[0];
  const float e = expf(x - M);
  float s = e;
#pragma unroll
  for (int o = 32; o; o >>= 1) s += __shfl_down(s, o);
  if ((l & 63) == 0) r2[l >> 6] = s;
  __syncthreads();
  if (l == 0) {
    float ss = 0.f;
    for (int i = 0; i < 8; ++i) ss += r2[i];
    r2[0] = ss;
  }
  __syncthreads();
  att[b * L + l] = e / r2[0];
}

// ---- 3. top-255 by rank (ties: lower index first), sorted by index via scan ----
__global__ __launch_bounds__(512) void k_select(const double* __restrict__ imp,
                                                const float* __restrict__ am,
                                                int* __restrict__ sel,
                                                float* __restrict__ out_mask,
                                                float* __restrict__ out_tome) {
  const int b = blockIdx.x, j = threadIdx.x;
  __shared__ double v[512];
  __shared__ int sc[512];
  const float* amb = am + b * L;
  const float aj = amb[j];
  double val;
  if (j == 0)
    val = (double)INFINITY;
  else
    val = (aj > -10.0f) ? imp[b * L + j] : 0.0;
  v[j] = val;
  __syncthreads();
  int r = 0;
  for (int t = 0; t < 512; ++t) {
    const double vt = v[t];
    r += (vt > val) || (vt == val && t < j);
  }
  const int f = (r < KSEL) ? 1 : 0;
  sc[j] = f;
  __syncthreads();
  for (int off = 1; off < 512; off <<= 1) {
    const int add = (j >= off) ? sc[j - off] : 0;
    __syncthreads();
    sc[j] += add;
    __syncthreads();
  }
  if (f) {
    const int pos = sc[j] - 1;  // 0..254
    sel[b * KSEL + pos] = j;
    out_mask[b * 256 + pos] = aj;
  }
  if (j == 0) out_mask[b * 256 + 255] = 0.0f;
  if (j < 256) out_tome[b * 256 + j] = 1.0f;
}

// ---- 4. gather preserved rows ----
__global__ __launch_bounds__(192) void k_gather(const float* __restrict__ hs,
                                                const int* __restrict__ sel,
                                                float* __restrict__ out_tok) {
  const int row = blockIdx.x;  // B*KSEL
  const int b = row / KSEL, p = row % KSEL;
  const int j = sel[row];
  const float4* src = reinterpret_cast<const float4*>(hs + ((size_t)b * L + j) * D);
  float4* dst = reinterpret_cast<float4*>(out_tok + ((size_t)b * 256 + p) * D);
  dst[threadIdx.x] = src[threadIdx.x];
}

// ---- 5. sentences[b,d] = sum_l att[b,l]*hs[b,l,d] ----
__global__ __launch_bounds__(768) void k_sent(const float* __restrict__ hs,
                                              const float* __restrict__ att,
                                              float* __restrict__ sent) {
  const int b = blockIdx.x, c = blockIdx.y, t = threadIdx.x;
  __shared__ float a[128];
  if (t < 128) a[t] = att[b * L + c * 128 + t];
  __syncthreads();
  const float* h0 = hs + ((size_t)b * L + c * 128) * D;
  float acc = 0.f;
  for (int l = 0; l < 128; ++l) acc += a[l] * h0[(size_t)l * D + t];
  atomicAdd(&sent[b * D + t], acc);
}

// ---- 6. q[b,u] = bq[u] + sent[b,:]@Wq[:,u]  (weight-stationary over b) ----
__global__ __launch_bounds__(1024) void k_q(const float* __restrict__ sent,
                                            const float* __restrict__ Wq,
                                            const float* __restrict__ bq,
                                            float* __restrict__ qg) {
  const int uc = blockIdx.x;  // 12 chunks of 64 columns
  const int ul = threadIdx.x & 63;
  const int bl = threadIdx.x >> 6;  // 0..15
  const int u = uc * 64 + ul;
#pragma unroll
  for (int half = 0; half < 2; ++half) {
    const int b = half * 16 + bl;
    const float* sb = sent + b * D;
    float acc = bq[u];
    for (int d = 0; d < D; ++d) acc += sb[d] * Wq[(size_t)d * D + u];
    qg[b * D + u] = acc;
  }
}

// ---- 7. A[b,h,d] = sum_c Wk[d,h*64+c]*q[b,h*64+c] ----
__global__ __launch_bounds__(1024) void k_A(const float* __restrict__ qg,
                                            const float* __restrict__ Wk,
                                            float* __restrict__ Ag) {
  const int h = blockIdx.x;   // 12
  const int dc = blockIdx.y;  // 12 chunks of 64 d
  const int dl = threadIdx.x & 63;
  const int bl = threadIdx.x >> 6;
  __shared__ float tile[64][65];  // Wk[dc*64+r, h*64+c], padded
  for (int i = threadIdx.x; i < 4096; i += 1024) {
    const int rr = i >> 6, cc = i & 63;
    tile[rr][cc] = Wk[(size_t)(dc * 64 + rr) * D + h * 64 + cc];
  }
  __syncthreads();
  const int d = dc * 64 + dl;
#pragma unroll
  for (int half = 0; half < 2; ++half) {
    const int b = half * 16 + bl;
    const float* qh = qg + b * D + h * 64;
    float acc = 0.f;
#pragma unroll
    for (int c = 0; c < 64; ++c) acc += tile[dl][c] * qh[c];
    Ag[((size_t)b * H + h) * D + d] = acc;
  }
}

// ---- 8. cb[b,h] = sum_c bk[h*64+c]*q[b,h*64+c] ----
__global__ __launch_bounds__(768) void k_cb(const float* __restrict__ qg,
                                            const float* __restrict__ bk,
                                            float* __restrict__ cbg) {
  const int b = blockIdx.x;
  const int h = threadIdx.x >> 6, c = threadIdx.x & 63;
  float v = bk[h * 64 + c] * qg[b * D + h * 64 + c];
#pragma unroll
  for (int o = 32; o; o >>= 1) v += __shfl_down(v, o);
  if (c == 0) cbg[b * H + h] = v;
}

// ---- 9. logits[b,h,l] = (x_l . A[b,h,:] + cb[b,h]) / 8 ----
__global__ __launch_bounds__(256) void k_logits(const float* __restrict__ hs,
                                                const float* __restrict__ Ag,
                                                const float* __restrict__ cbg,
                                                float* __restrict__ lg) {
  const int b = blockIdx.x, ch = blockIdx.y;  // 16 chunks of 32 rows
  __shared__ float A[H * D];                  // 36 KB
  for (int i = threadIdx.x; i < H * D; i += 256) A[i] = Ag[(size_t)b * H * D + i];
  __syncthreads();
  const int wave = threadIdx.x >> 6, lane = threadIdx.x & 63;
  const float* h0 = hs + (size_t)b * L * D;
  for (int li = 0; li < 8; ++li) {
    const int l = ch * 32 + li * 4 + wave;
    const float* xr = h0 + (size_t)l * D;
    float xv[12];
#pragma unroll
    for (int k = 0; k < 12; ++k) xv[k] = xr[lane + 64 * k];
#pragma unroll
    for (int h = 0; h < H; ++h) {
      float a = 0.f;
#pragma unroll
      for (int k = 0; k < 12; ++k) a += xv[k] * A[h * D + lane + 64 * k];
#pragma unroll
      for (int o = 32; o; o >>= 1) a += __shfl_down(a, o);
      if (lane == 0) lg[((size_t)b * H + h) * L + l] = (a + cbg[b * H + h]) * 0.125f;
    }
  }
}

// ---- 10. w = softmax over l (with key padding) in place ----
__global__ __launch_bounds__(512) void k_softw(float* __restrict__ lg,
                                               const float* __restrict__ am) {
  const int b = blockIdx.x, h = blockIdx.y, l = threadIdx.x;
  float* row = lg + ((size_t)b * H + h) * L;
  __shared__ float r1[8], r2[8];
  const float aml = am[b * L + l];
  const float x = (aml < -10.0f) ? -INFINITY : row[l];
  float m = x;
#pragma unroll
  for (int o = 32; o; o >>= 1) m = fmaxf(m, __shfl_down(m, o));
  if ((l & 63) == 0) r1[l >> 6] = m;
  __syncthreads();
  if (l == 0) {
    float mm = r1[0];
    for (int i = 1; i < 8; ++i) mm = fmaxf(mm, r1[i]);
    r1[0] = mm;
  }
  __syncthreads();
  const float M = r1[0];
  const float e = expf(x - M);
  float s = e;
#pragma unroll
  for (int o = 32; o; o >>= 1) s += __shfl_down(s, o);
  if ((l & 63) == 0) r2[l >> 6] = s;
  __syncthreads();
  if (l == 0) {
    float ss = 0.f;
    for (int i = 0; i < 8; ++i) ss += r2[i];
    r2[0] = ss;
  }
  __syncthreads();
  row[l] = e / r2[0];
}

// ---- 11. y[b,h,d] = sum_l w[b,h,l]*x[b,l,d] ----
__global__ __launch_bounds__(768) void k_y(const float* __restrict__ hs,
                                           const float* __restrict__ wg,
                                           float* __restrict__ y) {
  const int b = blockIdx.x, c = blockIdx.y, t = threadIdx.x;  // c: 4 chunks of 128 l
  __shared__ float w[12 * 128];
  for (int i = t; i < 12 * 128; i += 768) {
    const int h = i >> 7, l = i & 127;
    w[i] = wg[((size_t)b * H + h) * L + c * 128 + l];
  }
  __syncthreads();
  const float* h0 = hs + ((size_t)b * L + c * 128) * D;
  float acc[12];
#pragma unroll
  for (int h = 0; h < 12; ++h) acc[h] = 0.f;
  for (int l = 0; l < 128; ++l) {
    const float x = h0[(size_t)l * D + t];
#pragma unroll
    for (int h = 0; h < 12; ++h) acc[h] += w[h * 128 + l] * x;
  }
#pragma unroll
  for (int h = 0; h < 12; ++h) atomicAdd(&y[((size_t)b * H + h) * D + t], acc[h]);
}

// ---- 12. ctx[b,h*64+c] = bv + sum_d y[b,h,d]*Wv[d,h*64+c] ----
__global__ __launch_bounds__(1024) void k_ctx(const float* __restrict__ y,
                                              const float* __restrict__ Wv,
                                              const float* __restrict__ bv,
                                              float* __restrict__ ctx) {
  const int h = blockIdx.x;
  const int c = threadIdx.x & 63, bl = threadIdx.x >> 6;
#pragma unroll
  for (int half = 0; half < 2; ++half) {
    const int b = half * 16 + bl;
    const float* yb = y + ((size_t)b * H + h) * D;
    float acc = bv[h * 64 + c];
    for (int d = 0; d < D; ++d) acc += yb[d] * Wv[(size_t)d * D + h * 64 + c];
    ctx[b * D + h * 64 + c] = acc;
  }
}

// ---- 13. new_token[b,d'] = bo + ctx[b,:]@Wo[:,d'] -> final_token row 255 ----
__global__ __launch_bounds__(1024) void k_out(const float* __restrict__ ctx,
                                              const float* __restrict__ Wo,
                                              const float* __restrict__ bo,
                                              float* __restrict__ out_tok) {
  const int dc = blockIdx.x;
  const int dl = threadIdx.x & 63, bl = threadIdx.x >> 6;
  const int dd = dc * 64 + dl;
#pragma unroll
  for (int half = 0; half < 2; ++half) {
    const int b = half * 16 + bl;
    const float* cb = ctx + b * D;
    float acc = bo[dd];
    for (int u = 0; u < D; ++u) acc += cb[u] * Wo[(size_t)u * D + dd];
    out_tok[((size_t)b * 256 + 255) * D + dd] = acc;
  }
}

extern "C" void kernel_launch(void* const* d_in, const int* in_sizes, int n_in,
                              void* d_out, int out_size, void* d_ws, size_t ws_size,
                              hipStream_t stream) {
  const float* hs = (const float*)d_in[0];
  const float* am = (const float*)d_in[1];
  const float* sas = (const float*)d_in[2];
  const float* Wq = (const float*)d_in[3];
  const float* bq = (const float*)d_in[4];
  const float* Wk = (const float*)d_in[5];
  const float* bk = (const float*)d_in[6];
  const float* Wv = (const float*)d_in[7];
  const float* bv = (const float*)d_in[8];
  const float* Wo = (const float*)d_in[9];
  const float* bo = (const float*)d_in[10];

  float* out_tok = (float*)d_out;                  // [B,256,D]
  float* out_mask = out_tok + (size_t)B * 256 * D; // [B,1,1,256]
  float* out_tome = out_mask + (size_t)B * 256;    // [B,256,1]

  char* ws = (char*)d_ws;
  double* imp = (double*)(ws + OFF_IMP);
  float* att = (float*)(ws + OFF_ATT);
  float* sent = (float*)(ws + OFF_SENT);
  float* qg = (float*)(ws + OFF_Q);
  float* Ag = (float*)(ws + OFF_A);
  float* cbg = (float*)(ws + OFF_CB);
  float* lg = (float*)(ws + OFF_LG);
  float* yg = (float*)(ws + OFF_Y);
  int* sel = (int*)(ws + OFF_SEL);
  float* ctx = (float*)(ws + OFF_CTX);

  hipMemsetAsync(d_ws, 0, WS_NEED, stream);

  k_imp<<<dim3(B, H, 4), 128, 0, stream>>>(sas, am, imp);
  k_att<<<B, 512, 0, stream>>>(am, att);
  k_select<<<B, 512, 0, stream>>>(imp, am, sel, out_mask, out_tome);
  k_gather<<<B * KSEL, 192, 0, stream>>>(hs, sel, out_tok);
  k_sent<<<dim3(B, 4), 768, 0, stream>>>(hs, att, sent);
  k_q<<<12, 1024, 0, stream>>>(sent, Wq, bq, qg);
  k_A<<<dim3(12, 12), 1024, 0, stream>>>(qg, Wk, Ag);
  k_cb<<<B, 768, 0, stream>>>(qg, bk, cbg);
  k_logits<<<dim3(B, 16), 256, 0, stream>>>(hs, Ag, cbg, lg);
  k_softw<<<dim3(B, H), 512, 0, stream>>>(lg, am);
  k_y<<<dim3(B, 4), 768, 0, stream>>>(hs, lg, yg);
  k_ctx<<<12, 1024, 0, stream>>>(yg, Wv, bv, ctx);
  k_out<<<12, 1024, 0, stream>>>(ctx, Wo, bo, out_tok);
}

// Round 2
// 962.765 us; speedup vs baseline: 1.1085x; 1.1085x over previous
//
#include <hip/hip_runtime.h>
#include <cstdint>
#include <cstddef>

#define B 32
#define H 12
#define L 512
#define D 768
#define KSEL 255

// workspace byte offsets -- atomic-target buffers packed first for one small memset
#define OFF_IMP   0          // float[B*L]      65536
#define OFF_SENT  65536      // float[B*D]      98304
#define OFF_Y     163840     // float[B*H*D]  1179648
#define MEMSET_BYTES 1343488
#define OFF_ATT   1343488    // float[B*L]      65536
#define OFF_Q     1409024    // float[B*D]      98304
#define OFF_A     1507328    // float[B*H*D]  1179648
#define OFF_CB    2686976    // float[B*H]       1536
#define OFF_LG    2688512    // float[B*H*L]   786432
#define OFF_SEL   3474944    // int[B*KSEL]     32640
#define OFF_CTX   3507584    // float[B*D]      98304

// ---- 1. imp[b,j] = sum_{h,l} amf[l]*sas[b,h,l,j]  (fp32; boundary gap >> atomic noise) ----
__global__ __launch_bounds__(128) void k_imp(const float* __restrict__ sas,
                                             const float* __restrict__ am,
                                             float* __restrict__ imp) {
  const int b = blockIdx.x, h = blockIdx.y, ch = blockIdx.z;  // ch: 4 chunks of 128 rows
  const int t = threadIdx.x;                                  // 128 threads, float4 each
  const float* base = sas + (((size_t)(b * H + h)) * L + (size_t)ch * 128) * L;
  const float* amb = am + b * L + ch * 128;
  float a0 = 0, a1 = 0, a2 = 0, a3 = 0;
#pragma unroll 8
  for (int l = 0; l < 128; ++l) {
    const float m = (amb[l] > -10.0f) ? 1.0f : 0.0f;
    const float4 v = reinterpret_cast<const float4*>(base + (size_t)l * L)[t];
    a0 += m * v.x;
    a1 += m * v.y;
    a2 += m * v.z;
    a3 += m * v.w;
  }
  float* ip = imp + b * L + t * 4;
  atomicAdd(ip + 0, a0);
  atomicAdd(ip + 1, a1);
  atomicAdd(ip + 2, a2);
  atomicAdd(ip + 3, a3);
}

// ---- 2. merged: att softmax + top-255 select (rank + scan) + mask/tome outputs ----
__global__ __launch_bounds__(512) void k_prep(const float* __restrict__ am,
                                              const float* __restrict__ imp,
                                              float* __restrict__ att,
                                              int* __restrict__ sel,
                                              float* __restrict__ out_mask,
                                              float* __restrict__ out_tome) {
  const int b = blockIdx.x, l = threadIdx.x;
  __shared__ float r1[8], r2[8];
  __shared__ float v[512];
  __shared__ int sc[512];
  const float aml = am[b * L + l];
  // --- softmax(am) -> att ---
  float m = aml;
#pragma unroll
  for (int o = 32; o; o >>= 1) m = fmaxf(m, __shfl_down(m, o));
  if ((l & 63) == 0) r1[l >> 6] = m;
  __syncthreads();
  if (l == 0) {
    float mm = r1[0];
    for (int i = 1; i < 8; ++i) mm = fmaxf(mm, r1[i]);
    r1[0] = mm;
  }
  __syncthreads();
  const float M = r1[0];
  const float e = expf(aml - M);
  float s = e;
#pragma unroll
  for (int o = 32; o; o >>= 1) s += __shfl_down(s, o);
  if ((l & 63) == 0) r2[l >> 6] = s;
  __syncthreads();
  if (l == 0) {
    float ss = 0.f;
    for (int i = 0; i < 8; ++i) ss += r2[i];
    r2[0] = ss;
  }
  __syncthreads();
  att[b * L + l] = e / r2[0];
  // --- selection: rank with index tie-break, then index-order compaction via scan ---
  float val;
  if (l == 0)
    val = INFINITY;
  else
    val = (aml > -10.0f) ? imp[b * L + l] : 0.0f;
  v[l] = val;
  __syncthreads();
  int r = 0;
  for (int t = 0; t < 512; ++t) {
    const float vt = v[t];
    r += (vt > val) || (vt == val && t < l);
  }
  const int f = (r < KSEL) ? 1 : 0;
  sc[l] = f;
  __syncthreads();
  for (int off = 1; off < 512; off <<= 1) {
    const int add = (l >= off) ? sc[l - off] : 0;
    __syncthreads();
    sc[l] += add;
    __syncthreads();
  }
  if (f) {
    const int pos = sc[l] - 1;  // 0..254
    sel[b * KSEL + pos] = l;
    out_mask[b * 256 + pos] = aml;
  }
  if (l == 0) out_mask[b * 256 + 255] = 0.0f;
  if (l < 256) out_tome[b * 256 + l] = 1.0f;
}

// ---- 3. gather preserved rows ----
__global__ __launch_bounds__(192) void k_gather(const float* __restrict__ hs,
                                                const int* __restrict__ sel,
                                                float* __restrict__ out_tok) {
  const int row = blockIdx.x;  // B*KSEL
  const int b = row / KSEL, p = row % KSEL;
  const int j = sel[row];
  const float4* src = reinterpret_cast<const float4*>(hs + ((size_t)b * L + j) * D);
  float4* dst = reinterpret_cast<float4*>(out_tok + ((size_t)b * 256 + p) * D);
  dst[threadIdx.x] = src[threadIdx.x];
}

// ---- 4. sentences[b,d] = sum_l att[b,l]*hs[b,l,d] ----
__global__ __launch_bounds__(768) void k_sent(const float* __restrict__ hs,
                                              const float* __restrict__ att,
                                              float* __restrict__ sent) {
  const int b = blockIdx.x, c = blockIdx.y, t = threadIdx.x;  // c: 8 chunks of 64 rows
  __shared__ float a[64];
  if (t < 64) a[t] = att[b * L + c * 64 + t];
  __syncthreads();
  const float* h0 = hs + ((size_t)b * L + c * 64) * D;
  float acc = 0.f;
  for (int l = 0; l < 64; ++l) acc += a[l] * h0[(size_t)l * D + t];
  atomicAdd(&sent[b * D + t], acc);
}

// ---- 5. q[b,u] = bq[u] + sent@Wq ; fused cb[b,h] = bk_h . q_h (head-aligned chunks) ----
__global__ __launch_bounds__(512) void k_q(const float* __restrict__ sent,
                                           const float* __restrict__ Wq,
                                           const float* __restrict__ bq,
                                           const float* __restrict__ bk,
                                           float* __restrict__ qg,
                                           float* __restrict__ cbg) {
  const int h = blockIdx.x;   // 12 head-aligned 64-col chunks
  const int bg = blockIdx.y;  // 2 groups of 16 b
  const int ul = threadIdx.x & 63;
  const int bl = threadIdx.x >> 6;  // 0..7
  const int u = h * 64 + ul;
  const float bku = bk[u];
#pragma unroll
  for (int half = 0; half < 2; ++half) {
    const int b = bg * 16 + half * 8 + bl;
    const float* sb = sent + b * D;
    float acc = bq[u];
    for (int d = 0; d < D; ++d) acc += sb[d] * Wq[(size_t)d * D + u];
    qg[b * D + u] = acc;
    float v = bku * acc;  // wave = one (b); reduce over ul
#pragma unroll
    for (int o = 32; o; o >>= 1) v += __shfl_down(v, o);
    if (ul == 0) cbg[b * H + h] = v;
  }
}

// ---- 6. A[b,h,d] = sum_c Wk[d,h*64+c]*q[b,h*64+c] ----
__global__ __launch_bounds__(1024) void k_A(const float* __restrict__ qg,
                                            const float* __restrict__ Wk,
                                            float* __restrict__ Ag) {
  const int h = blockIdx.x;   // 12
  const int dc = blockIdx.y;  // 12 chunks of 64 d
  const int dl = threadIdx.x & 63;
  const int bl = threadIdx.x >> 6;
  __shared__ float tile[64][65];  // Wk[dc*64+r, h*64+c], padded
  for (int i = threadIdx.x; i < 4096; i += 1024) {
    const int rr = i >> 6, cc = i & 63;
    tile[rr][cc] = Wk[(size_t)(dc * 64 + rr) * D + h * 64 + cc];
  }
  __syncthreads();
  const int d = dc * 64 + dl;
#pragma unroll
  for (int half = 0; half < 2; ++half) {
    const int b = half * 16 + bl;
    const float* qh = qg + b * D + h * 64;
    float acc = 0.f;
#pragma unroll
    for (int c = 0; c < 64; ++c) acc += tile[dl][c] * qh[c];
    Ag[((size_t)b * H + h) * D + d] = acc;
  }
}

// ---- 7. logits[b,h,l] = (x_l . A[b,h,:] + cb[b,h]) / 8 ----
__global__ __launch_bounds__(256) void k_logits(const float* __restrict__ hs,
                                                const float* __restrict__ Ag,
                                                const float* __restrict__ cbg,
                                                float* __restrict__ lg) {
  const int b = blockIdx.x, ch = blockIdx.y;  // 16 chunks of 32 rows
  __shared__ float A[H * D];                  // 36 KB
  for (int i = threadIdx.x; i < H * D; i += 256) A[i] = Ag[(size_t)b * H * D + i];
  __syncthreads();
  const int wave = threadIdx.x >> 6, lane = threadIdx.x & 63;
  const float* h0 = hs + (size_t)b * L * D;
  for (int li = 0; li < 8; ++li) {
    const int l = ch * 32 + li * 4 + wave;
    const float* xr = h0 + (size_t)l * D;
    float xv[12];
#pragma unroll
    for (int k = 0; k < 12; ++k) xv[k] = xr[lane + 64 * k];
#pragma unroll
    for (int h = 0; h < H; ++h) {
      float a = 0.f;
#pragma unroll
      for (int k = 0; k < 12; ++k) a += xv[k] * A[h * D + lane + 64 * k];
#pragma unroll
      for (int o = 32; o; o >>= 1) a += __shfl_down(a, o);
      if (lane == 0) lg[((size_t)b * H + h) * L + l] = (a + cbg[b * H + h]) * 0.125f;
    }
  }
}

// ---- 8. merged softmax + y: y[b,h,d] = sum_l softmax(lg)[b,h,l]*x[b,l,d] ----
__global__ __launch_bounds__(768) void k_ysoft(const float* __restrict__ hs,
                                               const float* __restrict__ lg,
                                               const float* __restrict__ am,
                                               float* __restrict__ y) {
  const int b = blockIdx.x, c = blockIdx.y, t = threadIdx.x;  // c: 4 chunks of 128 l
  __shared__ float wl[H * L];   // 24 KB raw (masked) logits
  __shared__ float Ms[H], Is[H];
  __shared__ float wn[H * 128];  // normalized weights for this chunk
  for (int i = t; i < H * L; i += 768) {
    const int l = i & (L - 1);
    const float aml = am[b * L + l];
    wl[i] = (aml < -10.0f) ? -INFINITY : lg[(size_t)b * H * L + i];
  }
  __syncthreads();
  {  // wave g == head h (768 = 12 waves of 64)
    const int h = t >> 6, lane = t & 63;
    float m = -INFINITY;
#pragma unroll
    for (int k = 0; k < 8; ++k) m = fmaxf(m, wl[h * L + lane + 64 * k]);
#pragma unroll
    for (int o = 32; o; o >>= 1) m = fmaxf(m, __shfl_xor(m, o));
    float s = 0.f;
#pragma unroll
    for (int k = 0; k < 8; ++k) s += expf(wl[h * L + lane + 64 * k] - m);
#pragma unroll
    for (int o = 32; o; o >>= 1) s += __shfl_xor(s, o);
    if (lane == 0) { Ms[h] = m; Is[h] = 1.0f / s; }
  }
  __syncthreads();
  for (int i = t; i < H * 128; i += 768) {
    const int h = i >> 7, l = i & 127;
    wn[i] = expf(wl[h * L + c * 128 + l] - Ms[h]) * Is[h];
  }
  __syncthreads();
  const float* h0 = hs + ((size_t)b * L + c * 128) * D;
  float acc[12];
#pragma unroll
  for (int h = 0; h < 12; ++h) acc[h] = 0.f;
  for (int l = 0; l < 128; ++l) {
    const float x = h0[(size_t)l * D + t];
#pragma unroll
    for (int h = 0; h < 12; ++h) acc[h] += wn[h * 128 + l] * x;
  }
#pragma unroll
  for (int h = 0; h < 12; ++h) atomicAdd(&y[((size_t)b * H + h) * D + t], acc[h]);
}

// ---- 9. ctx[b,h*64+c] = bv + sum_d y[b,h,d]*Wv[d,h*64+c] ----
__global__ __launch_bounds__(512) void k_ctx(const float* __restrict__ y,
                                             const float* __restrict__ Wv,
                                             const float* __restrict__ bv,
                                             float* __restrict__ ctx) {
  const int h = blockIdx.x, bg = blockIdx.y;
  const int c = threadIdx.x & 63, bl = threadIdx.x >> 6;  // 0..7
#pragma unroll
  for (int half = 0; half < 2; ++half) {
    const int b = bg * 16 + half * 8 + bl;
    const float* yb = y + ((size_t)b * H + h) * D;
    float acc = bv[h * 64 + c];
    for (int d = 0; d < D; ++d) acc += yb[d] * Wv[(size_t)d * D + h * 64 + c];
    ctx[b * D + h * 64 + c] = acc;
  }
}

// ---- 10. new_token[b,d'] = bo + ctx@Wo -> final_token row 255 ----
__global__ __launch_bounds__(512) void k_out(const float* __restrict__ ctx,
                                             const float* __restrict__ Wo,
                                             const float* __restrict__ bo,
                                             float* __restrict__ out_tok) {
  const int dc = blockIdx.x, bg = blockIdx.y;
  const int dl = threadIdx.x & 63, bl = threadIdx.x >> 6;
  const int dd = dc * 64 + dl;
#pragma unroll
  for (int half = 0; half < 2; ++half) {
    const int b = bg * 16 + half * 8 + bl;
    const float* cb = ctx + b * D;
    float acc = bo[dd];
    for (int u = 0; u < D; ++u) acc += cb[u] * Wo[(size_t)u * D + dd];
    out_tok[((size_t)b * 256 + 255) * D + dd] = acc;
  }
}

extern "C" void kernel_launch(void* const* d_in, const int* in_sizes, int n_in,
                              void* d_out, int out_size, void* d_ws, size_t ws_size,
                              hipStream_t stream) {
  const float* hs = (const float*)d_in[0];
  const float* am = (const float*)d_in[1];
  const float* sas = (const float*)d_in[2];
  const float* Wq = (const float*)d_in[3];
  const float* bq = (const float*)d_in[4];
  const float* Wk = (const float*)d_in[5];
  const float* bk = (const float*)d_in[6];
  const float* Wv = (const float*)d_in[7];
  const float* bv = (const float*)d_in[8];
  const float* Wo = (const float*)d_in[9];
  const float* bo = (const float*)d_in[10];

  float* out_tok = (float*)d_out;                   // [B,256,D]
  float* out_mask = out_tok + (size_t)B * 256 * D;  // [B,1,1,256]
  float* out_tome = out_mask + (size_t)B * 256;     // [B,256,1]

  char* ws = (char*)d_ws;
  float* imp = (float*)(ws + OFF_IMP);
  float* sent = (float*)(ws + OFF_SENT);
  float* yg = (float*)(ws + OFF_Y);
  float* att = (float*)(ws + OFF_ATT);
  float* qg = (float*)(ws + OFF_Q);
  float* Ag = (float*)(ws + OFF_A);
  float* cbg = (float*)(ws + OFF_CB);
  float* lg = (float*)(ws + OFF_LG);
  int* sel = (int*)(ws + OFF_SEL);
  float* ctx = (float*)(ws + OFF_CTX);

  hipMemsetAsync(d_ws, 0, MEMSET_BYTES, stream);

  k_imp<<<dim3(B, H, 4), 128, 0, stream>>>(sas, am, imp);
  k_prep<<<B, 512, 0, stream>>>(am, imp, att, sel, out_mask, out_tome);
  k_gather<<<B * KSEL, 192, 0, stream>>>(hs, sel, out_tok);
  k_sent<<<dim3(B, 8), 768, 0, stream>>>(hs, att, sent);
  k_q<<<dim3(12, 2), 512, 0, stream>>>(sent, Wq, bq, bk, qg, cbg);
  k_A<<<dim3(12, 12), 1024, 0, stream>>>(qg, Wk, Ag);
  k_logits<<<dim3(B, 16), 256, 0, stream>>>(hs, Ag, cbg, lg);
  k_ysoft<<<dim3(B, 4), 768, 0, stream>>>(hs, lg, am, yg);
  k_ctx<<<dim3(12, 2), 512, 0, stream>>>(yg, Wv, bv, ctx);
  k_out<<<dim3(12, 2), 512, 0, stream>>>(ctx, Wo, bo, out_tok);
}